// Round 1
// baseline (29235.944 us; speedup 1.0000x reference)
//
#include <hip/hip_runtime.h>
#include <hip/hip_bf16.h>
#include <cstdint>
#include <cstddef>

// Problem constants
#define BATCH 64
#define LSEQ 200
#define HID 256
#define NH 8
#define DH 256            // per-head dim = HID (key_query_size_hidden = hidden_size)
#define HD (NH*DH)        // 2048
#define MROWS (BATCH*LSEQ)   // 12800
#define MTOT 990          // sum_{w=1..5} (L-w+1)
#define EPS 1e-5f

// ---------------- helpers ----------------
__device__ __forceinline__ float to_f32(float x) { return x; }
__device__ __forceinline__ float to_f32(__hip_bfloat16 x) { return __bfloat162float(x); }
__device__ __forceinline__ void store_val(float* p, float v) { *p = v; }
__device__ __forceinline__ void store_val(__hip_bfloat16* p, float v) { *p = __float2bfloat16(v); }

// ---------------- generic tiled GEMM: C[M,N] = A[M,K] @ W[K,N] + bias ----------------
// block 256 threads (16x16), tile 64x64, K-step 16, each thread 4x4.
template<typename TA, typename TO, bool RELU>
__global__ __launch_bounds__(256) void gemm_bias(
    const TA* __restrict__ A, const float* __restrict__ W,
    const float* __restrict__ bias, TO* __restrict__ C,
    int M, int N, int K)
{
    __shared__ float As[16][68];   // [kk][m_local], pad 68 (16B-aligned rows, 2-way banks)
    __shared__ float Ws[16][68];   // [kk][n_local]
    const int t  = threadIdx.x;
    const int m0 = blockIdx.y * 64;
    const int n0 = blockIdx.x * 64;
    const int ty = t >> 4, tx = t & 15;

    float acc[4][4];
    #pragma unroll
    for (int i = 0; i < 4; ++i)
        #pragma unroll
        for (int j = 0; j < 4; ++j) acc[i][j] = 0.f;

    for (int k0 = 0; k0 < K; k0 += 16) {
        #pragma unroll
        for (int i = 0; i < 4; ++i) {           // A tile: 64 rows x 16 k
            int idx = t + i * 256;
            int kk = idx & 15, ml = idx >> 4;
            As[kk][ml] = to_f32(A[(size_t)(m0 + ml) * K + k0 + kk]);
        }
        #pragma unroll
        for (int i = 0; i < 4; ++i) {           // W tile: 16 k x 64 n
            int idx = t + i * 256;
            int nl = idx & 63, kk = idx >> 6;
            Ws[kk][nl] = W[(size_t)(k0 + kk) * N + n0 + nl];
        }
        __syncthreads();
        #pragma unroll
        for (int kk = 0; kk < 16; ++kk) {
            float4 a4 = *(const float4*)&As[kk][ty * 4];
            float4 b4 = *(const float4*)&Ws[kk][tx * 4];
            float a[4] = {a4.x, a4.y, a4.z, a4.w};
            float b[4] = {b4.x, b4.y, b4.z, b4.w};
            #pragma unroll
            for (int i = 0; i < 4; ++i)
                #pragma unroll
                for (int j = 0; j < 4; ++j) acc[i][j] += a[i] * b[j];
        }
        __syncthreads();
    }
    #pragma unroll
    for (int i = 0; i < 4; ++i) {
        int m = m0 + ty * 4 + i;
        #pragma unroll
        for (int j = 0; j < 4; ++j) {
            int n = n0 + tx * 4 + j;
            float v = acc[i][j] + bias[n];
            if (RELU) v = fmaxf(v, 0.f);
            store_val(&C[(size_t)m * N + n], v);
        }
    }
}

// ---------------- fused area-attention (flash-style, on-the-fly pooling) ----------------
// grid: (13 q-tiles, B*NH).  block: 256 threads.
// Q tile = 16 rows; M tile = 32 pooled positions.  O may alias Q (block reads only its own Q tile).
#define QT 16
#define MT 32
#define KPAD 260   // DH + 4: keeps float4 row alignment, odd-ish banking

__device__ __forceinline__ void area_decode(int m, int& w, int& start) {
    if (m < 200)      { w = 1; start = m; }
    else if (m < 399) { w = 2; start = m - 200; }
    else if (m < 597) { w = 3; start = m - 399; }
    else if (m < 794) { w = 4; start = m - 597; }
    else              { w = 5; start = m - 794; }
}

__global__ __launch_bounds__(256) void attn_fused(
    const __hip_bfloat16* __restrict__ Q,
    const __hip_bfloat16* __restrict__ K,
    const __hip_bfloat16* __restrict__ V,
    __hip_bfloat16* __restrict__ O)   // may alias Q
{
    const int bh = blockIdx.y;
    const int b = bh >> 3, h = bh & 7;
    const int q0 = blockIdx.x * QT;
    const int rows = min(QT, LSEQ - q0);
    const int t = threadIdx.x;

    __shared__ float qs[QT][KPAD];     // 16.6 KB
    __shared__ float kv[MT][KPAD];     // 33.3 KB (pooled K, then pooled V)
    __shared__ float p[QT][MT];        // 2 KB
    __shared__ float mrow[QT], lrow[QT], arow[QT];

    const size_t strideL = HD;
    const __hip_bfloat16* qbase = Q + ((size_t)b * LSEQ) * strideL + h * DH;
    const __hip_bfloat16* kbase = K + ((size_t)b * LSEQ) * strideL + h * DH;
    const __hip_bfloat16* vbase = V + ((size_t)b * LSEQ) * strideL + h * DH;

    // load Q tile (d = t, rows = i)
    #pragma unroll
    for (int i = 0; i < QT; ++i) {
        float val = 0.f;
        if (i < rows) val = __bfloat162float(qbase[(size_t)(q0 + i) * strideL + t]);
        qs[i][t] = val;
    }
    if (t < QT) { mrow[t] = -1e30f; lrow[t] = 0.f; }

    const int r_own = t >> 4;
    const int c0 = (t & 15) * 16;
    float o_acc[16];
    #pragma unroll
    for (int i = 0; i < 16; ++i) o_acc[i] = 0.f;

    const float scale = 0.0625f;   // 1/sqrt(256)
    const int ntiles = (MTOT + MT - 1) / MT;   // 31

    for (int mt = 0; mt < ntiles; ++mt) {
        const int m0 = mt * MT;
        __syncthreads();   // kv/p free from previous iteration (and qs stores visible on iter 0)
        // stage pooled K (max over window), d = t, j = i
        #pragma unroll
        for (int i = 0; i < MT; ++i) {
            int m = m0 + i;
            float val = 0.f;
            if (m < MTOT) {
                int w, start; area_decode(m, w, start);
                float mx = -1e30f;
                for (int u = 0; u < w; ++u)
                    mx = fmaxf(mx, __bfloat162float(kbase[(size_t)(start + u) * strideL + t]));
                val = mx;
            }
            kv[i][t] = val;
        }
        __syncthreads();
        // logits: thread (r = t>>4, j0 = t&15) computes p[r][j0], p[r][j0+16]
        {
            const int r = t >> 4;
            const int j0 = t & 15;
            float acc0 = 0.f, acc1 = 0.f;
            #pragma unroll 4
            for (int d = 0; d < DH; d += 4) {
                float4 a4 = *(const float4*)&qs[r][d];
                float4 k0v = *(const float4*)&kv[j0][d];
                float4 k1v = *(const float4*)&kv[j0 + 16][d];
                acc0 += a4.x * k0v.x + a4.y * k0v.y + a4.z * k0v.z + a4.w * k0v.w;
                acc1 += a4.x * k1v.x + a4.y * k1v.y + a4.z * k1v.z + a4.w * k1v.w;
            }
            bool rv = (r < rows);
            p[r][j0]      = (rv && (m0 + j0      < MTOT)) ? acc0 * scale : -1e30f;
            p[r][j0 + 16] = (rv && (m0 + j0 + 16 < MTOT)) ? acc1 * scale : -1e30f;
        }
        __syncthreads();
        // online softmax: thread r handles row r
        if (t < QT) {
            const int r = t;
            float mx = mrow[r];
            #pragma unroll
            for (int j = 0; j < MT; ++j) mx = fmaxf(mx, p[r][j]);
            float alpha = __expf(mrow[r] - mx);
            float s = 0.f;
            #pragma unroll
            for (int j = 0; j < MT; ++j) {
                float e = __expf(p[r][j] - mx);
                p[r][j] = e;
                s += e;
            }
            lrow[r] = lrow[r] * alpha + s;
            mrow[r] = mx;
            arow[r] = alpha;
        }
        __syncthreads();
        // rescale O, then stage pooled V (sum) over kv
        {
            float alpha = arow[r_own];
            #pragma unroll
            for (int i = 0; i < 16; ++i) o_acc[i] *= alpha;
        }
        #pragma unroll
        for (int i = 0; i < MT; ++i) {
            int m = m0 + i;
            float val = 0.f;
            if (m < MTOT) {
                int w, start; area_decode(m, w, start);
                float s = 0.f;
                for (int u = 0; u < w; ++u)
                    s += __bfloat162float(vbase[(size_t)(start + u) * strideL + t]);
                val = s;
            }
            kv[i][t] = val;
        }
        __syncthreads();
        // PV: o[r_own][c0..c0+15] += p[r_own][j] * Vp[j][c0..]
        #pragma unroll 4
        for (int j = 0; j < MT; ++j) {
            float pj = p[r_own][j];
            const float4* vr = (const float4*)&kv[j][c0];
            float4 v0 = vr[0], v1 = vr[1], v2 = vr[2], v3 = vr[3];
            o_acc[0]  += pj * v0.x; o_acc[1]  += pj * v0.y; o_acc[2]  += pj * v0.z; o_acc[3]  += pj * v0.w;
            o_acc[4]  += pj * v1.x; o_acc[5]  += pj * v1.y; o_acc[6]  += pj * v1.z; o_acc[7]  += pj * v1.w;
            o_acc[8]  += pj * v2.x; o_acc[9]  += pj * v2.y; o_acc[10] += pj * v2.z; o_acc[11] += pj * v2.w;
            o_acc[12] += pj * v3.x; o_acc[13] += pj * v3.y; o_acc[14] += pj * v3.z; o_acc[15] += pj * v3.w;
        }
    }
    __syncthreads();
    if (r_own < rows) {
        float inv_l = 1.f / lrow[r_own];
        __hip_bfloat16* obase = O + ((size_t)b * LSEQ) * strideL + h * DH;
        #pragma unroll
        for (int i = 0; i < 16; ++i)
            obase[(size_t)(q0 + r_own) * strideL + c0 + i] = __float2bfloat16(o_acc[i] * inv_l);
    }
}

// ---------------- residual + LayerNorm (no affine): Out = LN(X + R) ----------------
__global__ __launch_bounds__(256) void residual_ln(
    const float* __restrict__ X, const float* __restrict__ R, float* __restrict__ Out)
{
    const int row = blockIdx.x;
    const int t = threadIdx.x;
    const size_t base = (size_t)row * HID;
    float v = X[base + t] + R[base + t];
    float s = v, q = v * v;
    #pragma unroll
    for (int o = 32; o > 0; o >>= 1) {
        s += __shfl_xor(s, o, 64);
        q += __shfl_xor(q, o, 64);
    }
    __shared__ float ss[4], sq[4];
    const int wave = t >> 6, lane = t & 63;
    if (lane == 0) { ss[wave] = s; sq[wave] = q; }
    __syncthreads();
    s = ss[0] + ss[1] + ss[2] + ss[3];
    q = sq[0] + sq[1] + sq[2] + sq[3];
    float mean = s * (1.f / HID);
    float var  = q * (1.f / HID) - mean * mean;
    Out[base + t] = (v - mean) * rsqrtf(var + EPS);
}

// ---------------- launch ----------------
extern "C" void kernel_launch(void* const* d_in, const int* in_sizes, int n_in,
                              void* d_out, int out_size, void* d_ws, size_t ws_size,
                              hipStream_t stream) {
    const float* hidden = (const float*)d_in[1];
    const float* Wq = (const float*)d_in[2];  const float* bq = (const float*)d_in[3];
    const float* Wk = (const float*)d_in[4];  const float* bk = (const float*)d_in[5];
    const float* Wv = (const float*)d_in[6];  const float* bv = (const float*)d_in[7];
    const float* Wo = (const float*)d_in[8];  const float* bo = (const float*)d_in[9];
    const float* W1 = (const float*)d_in[10]; const float* b1 = (const float*)d_in[11];
    const float* W2 = (const float*)d_in[12]; const float* b2 = (const float*)d_in[13];
    float* out = (float*)d_out;

    // workspace layout (bytes)
    constexpr size_t SZ_BF  = (size_t)MROWS * HD * 2;        // 52,428,800
    constexpr size_t SZ_F32 = (size_t)MROWS * HID * 4;       // 13,107,200
    constexpr size_t SZ_FFN = (size_t)MROWS * (4 * HID) * 4; // 52,428,800
    char* ws = (char*)d_ws;
    size_t off = 0;
    __hip_bfloat16* kb = (__hip_bfloat16*)(ws + off); off += SZ_BF;
    __hip_bfloat16* vb = (__hip_bfloat16*)(ws + off); off += SZ_BF;
    __hip_bfloat16* qo = (__hip_bfloat16*)(ws + off); off += SZ_BF;  // q, then attn_out in-place
    float* attn1 = (float*)(ws + off); off += SZ_F32;
    float* attn2 = (float*)(ws + off); off += SZ_F32;
    float* proj  = (float*)(ws + off); off += SZ_F32;
    float* ffn   = (float*)(ws + off); off += SZ_FFN;
    if (ws_size < off) return;  // insufficient workspace -> fail validation without OOB writes

    dim3 blk(256);
    const dim3 gProj(HD / 64, MROWS / 64);     // (32, 200)
    const dim3 gOut(HID / 64, MROWS / 64);     // (4, 200)
    const dim3 gF1(4 * HID / 64, MROWS / 64);  // (16, 200)
    const dim3 gAttn((LSEQ + QT - 1) / QT, BATCH * NH);   // (13, 512)

    // MHA1 (k/v shared with MHA2)
    gemm_bias<float, __hip_bfloat16, false><<<gProj, blk, 0, stream>>>(hidden, Wk, bk, kb, MROWS, HD, HID);
    gemm_bias<float, __hip_bfloat16, false><<<gProj, blk, 0, stream>>>(hidden, Wv, bv, vb, MROWS, HD, HID);
    gemm_bias<float, __hip_bfloat16, false><<<gProj, blk, 0, stream>>>(hidden, Wq, bq, qo, MROWS, HD, HID);
    attn_fused<<<gAttn, blk, 0, stream>>>(qo, kb, vb, qo);
    gemm_bias<__hip_bfloat16, float, false><<<gOut, blk, 0, stream>>>(qo, Wo, bo, proj, MROWS, HID, HD);
    residual_ln<<<MROWS, blk, 0, stream>>>(proj, hidden, attn1);

    // MHA2 (q from attn1; k/v reused)
    gemm_bias<float, __hip_bfloat16, false><<<gProj, blk, 0, stream>>>(attn1, Wq, bq, qo, MROWS, HD, HID);
    attn_fused<<<gAttn, blk, 0, stream>>>(qo, kb, vb, qo);
    gemm_bias<__hip_bfloat16, float, false><<<gOut, blk, 0, stream>>>(qo, Wo, bo, proj, MROWS, HID, HD);
    residual_ln<<<MROWS, blk, 0, stream>>>(proj, attn1, attn2);

    // FFN
    gemm_bias<float, float, true><<<gF1, blk, 0, stream>>>(attn2, W1, b1, ffn, MROWS, 4 * HID, HID);
    gemm_bias<float, float, false><<<gOut, blk, 0, stream>>>(ffn, W2, b2, proj, MROWS, HID, 4 * HID);
    residual_ln<<<MROWS, blk, 0, stream>>>(proj, attn2, out);
}

// Round 2
// 4227.334 us; speedup vs baseline: 6.9159x; 6.9159x over previous
//
#include <hip/hip_runtime.h>
#include <hip/hip_bf16.h>
#include <cstdint>
#include <cstddef>

// Problem constants
#define BATCH 64
#define LSEQ 200
#define HID 256
#define NH 8
#define DH 256            // per-head dim = HID
#define HD (NH*DH)        // 2048
#define MROWS (BATCH*LSEQ)   // 12800
#define MTOT 990          // sum_{w=1..5} (L-w+1)
#define EPS 1e-5f

typedef unsigned short ushort_t;
typedef __attribute__((ext_vector_type(8))) short bf16x8;   // 8 bf16 = 4 VGPR (MFMA A/B frag)
typedef __attribute__((ext_vector_type(4))) float f32x4;    // MFMA C/D frag

__device__ __forceinline__ float b2f(ushort_t u) {
    union { unsigned int i; float f; } c; c.i = ((unsigned int)u) << 16; return c.f;
}
__device__ __forceinline__ ushort_t f2b(float f) {
    __hip_bfloat16 h = __float2bfloat16(f);
    union { __hip_bfloat16 h; ushort_t u; } c; c.h = h; return c.u;
}

// ---------------- helpers for generic GEMM ----------------
__device__ __forceinline__ float to_f32(float x) { return x; }
__device__ __forceinline__ float to_f32(__hip_bfloat16 x) { return __bfloat162float(x); }
__device__ __forceinline__ void store_val(float* p, float v) { *p = v; }
__device__ __forceinline__ void store_val(__hip_bfloat16* p, float v) { *p = __float2bfloat16(v); }

// ---------------- generic tiled GEMM: C[M,N] = A[M,K] @ W[K,N] + bias ----------------
template<typename TA, typename TO, bool RELU>
__global__ __launch_bounds__(256) void gemm_bias(
    const TA* __restrict__ A, const float* __restrict__ W,
    const float* __restrict__ bias, TO* __restrict__ C,
    int M, int N, int K)
{
    __shared__ float As[16][68];
    __shared__ float Ws[16][68];
    const int t  = threadIdx.x;
    const int m0 = blockIdx.y * 64;
    const int n0 = blockIdx.x * 64;
    const int ty = t >> 4, tx = t & 15;

    float acc[4][4];
    #pragma unroll
    for (int i = 0; i < 4; ++i)
        #pragma unroll
        for (int j = 0; j < 4; ++j) acc[i][j] = 0.f;

    for (int k0 = 0; k0 < K; k0 += 16) {
        #pragma unroll
        for (int i = 0; i < 4; ++i) {
            int idx = t + i * 256;
            int kk = idx & 15, ml = idx >> 4;
            As[kk][ml] = to_f32(A[(size_t)(m0 + ml) * K + k0 + kk]);
        }
        #pragma unroll
        for (int i = 0; i < 4; ++i) {
            int idx = t + i * 256;
            int nl = idx & 63, kk = idx >> 6;
            Ws[kk][nl] = W[(size_t)(k0 + kk) * N + n0 + nl];
        }
        __syncthreads();
        #pragma unroll
        for (int kk = 0; kk < 16; ++kk) {
            float4 a4 = *(const float4*)&As[kk][ty * 4];
            float4 b4 = *(const float4*)&Ws[kk][tx * 4];
            float a[4] = {a4.x, a4.y, a4.z, a4.w};
            float b[4] = {b4.x, b4.y, b4.z, b4.w};
            #pragma unroll
            for (int i = 0; i < 4; ++i)
                #pragma unroll
                for (int j = 0; j < 4; ++j) acc[i][j] += a[i] * b[j];
        }
        __syncthreads();
    }
    #pragma unroll
    for (int i = 0; i < 4; ++i) {
        int m = m0 + ty * 4 + i;
        #pragma unroll
        for (int j = 0; j < 4; ++j) {
            int n = n0 + tx * 4 + j;
            float v = acc[i][j] + bias[n];
            if (RELU) v = fmaxf(v, 0.f);
            store_val(&C[(size_t)m * N + n], v);
        }
    }
}

// ---------------- area decode: pooled index m -> (window w, start st) ----------------
__device__ __forceinline__ void area_decode(int m, int& w, int& st) {
    if (m < 200)      { w = 1; st = m; }
    else if (m < 399) { w = 2; st = m - 200; }
    else if (m < 597) { w = 3; st = m - 399; }
    else if (m < 794) { w = 4; st = m - 597; }
    else              { w = 5; st = m - 794; }
}

// ---------------- MFMA fused area-attention ----------------
// grid (4 q-tiles of 64, B*NH).  block 256 = 4 waves; wave owns a 16-row Q strip.
// M swept in tiles of 64 (16 iters over padded 1024).
// LDS: Ks[64][264] (pooled-max K, row-major [m][d], +8 pad) = 33,792 B
//      Vs[256][72] (pooled-sum V, TRANSPOSED [d][m], +8 pad) = 36,864 B
//      Ps[4][16][72] (per-wave P in bf16 for A-frag reload)   =  9,216 B   -> 79,872 B (2 blocks/CU)
__global__ __launch_bounds__(256, 2) void attn_mfma(
    const ushort_t* __restrict__ Q, const ushort_t* __restrict__ K,
    const ushort_t* __restrict__ V, ushort_t* __restrict__ O)  // O may alias Q (disjoint rows/head)
{
    const int bh = blockIdx.y;
    const int b = bh >> 3, h = bh & 7;
    const int q0 = blockIdx.x * 64;
    const int t = threadIdx.x;
    const int wave = t >> 6, lane = t & 63;
    const int l15 = lane & 15, lq = lane >> 4;

    __shared__ ushort_t KsU[64][264];
    __shared__ ushort_t VsU[256][72];
    __shared__ ushort_t PsU[4][16][72];

    const ushort_t* kb = K + (size_t)(b * LSEQ) * HD + h * DH;
    const ushort_t* vb = V + (size_t)(b * LSEQ) * HD + h * DH;

    // Q fragments (A-operand layout: row = lane&15, k = 8*quad + j), held in regs all kernel
    const int qrow = q0 + wave * 16 + l15;
    bf16x8 qf[8];
    if (qrow < LSEQ) {
        const ushort_t* qp = Q + (size_t)(b * LSEQ + qrow) * HD + h * DH + 8 * lq;
        #pragma unroll
        for (int g = 0; g < 8; ++g) qf[g] = *(const bf16x8*)(qp + 32 * g);
    } else {
        bf16x8 zf = {0,0,0,0,0,0,0,0};
        #pragma unroll
        for (int g = 0; g < 8; ++g) qf[g] = zf;
    }

    f32x4 zero4 = {0.f, 0.f, 0.f, 0.f};
    f32x4 oacc[16];
    #pragma unroll
    for (int i = 0; i < 16; ++i) oacc[i] = zero4;
    float m_st[4], l_st[4];
    #pragma unroll
    for (int e = 0; e < 4; ++e) { m_st[e] = -1e30f; l_st[e] = 0.f; }

    const float scale = 0.0625f;  // 1/sqrt(256)

    for (int mt = 0; mt < 16; ++mt) {
        const int m0 = mt * 64;
        __syncthreads();   // previous iter's Ks/Vs fragment reads complete

        // ---- stage pooled K (window max), layout [m][d]; lane -> 4 d's, wave -> 16 m's ----
        {
            const int dq = lane * 4;
            for (int i = 0; i < 16; ++i) {
                const int ml = wave * 16 + i;
                const int m = m0 + ml;
                float x0 = 0.f, x1 = 0.f, x2 = 0.f, x3 = 0.f;
                if (m < MTOT) {
                    int w, st; area_decode(m, w, st);
                    const ushort_t* p = kb + (size_t)st * HD + dq;
                    ushort4 r = *(const ushort4*)p;
                    x0 = b2f(r.x); x1 = b2f(r.y); x2 = b2f(r.z); x3 = b2f(r.w);
                    for (int u = 1; u < w; ++u) {
                        r = *(const ushort4*)(p + (size_t)u * HD);
                        x0 = fmaxf(x0, b2f(r.x)); x1 = fmaxf(x1, b2f(r.y));
                        x2 = fmaxf(x2, b2f(r.z)); x3 = fmaxf(x3, b2f(r.w));
                    }
                }
                ushort4 o4; o4.x = f2b(x0); o4.y = f2b(x1); o4.z = f2b(x2); o4.w = f2b(x3);
                *(ushort4*)&KsU[ml][dq] = o4;
            }
        }
        // ---- stage pooled V (window sum), TRANSPOSED [d][m]; lane -> m, wave -> 64 d's ----
        {
            const int ml = lane;
            const int m = m0 + ml;
            int w = 1, st = 0;
            const bool val = (m < MTOT);
            if (val) area_decode(m, w, st);
            #pragma unroll
            for (int dc = 0; dc < 4; ++dc) {
                const int d0 = wave * 64 + dc * 16;
                float acc[16];
                #pragma unroll
                for (int k = 0; k < 16; ++k) acc[k] = 0.f;
                if (val) {
                    for (int u = 0; u < w; ++u) {
                        const ushort_t* p = vb + (size_t)(st + u) * HD + d0;
                        #pragma unroll
                        for (int qd = 0; qd < 4; ++qd) {
                            ushort4 r = *(const ushort4*)(p + 4 * qd);
                            acc[4*qd+0] += b2f(r.x); acc[4*qd+1] += b2f(r.y);
                            acc[4*qd+2] += b2f(r.z); acc[4*qd+3] += b2f(r.w);
                        }
                    }
                }
                #pragma unroll
                for (int k = 0; k < 16; ++k) VsU[d0 + k][ml] = f2b(acc[k]);
            }
        }
        __syncthreads();

        // ---- QK^T: wave's 16q strip x 64 m, 4 tiles of 16x16, k=256 ----
        f32x4 sacc[4];
        #pragma unroll
        for (int ms = 0; ms < 4; ++ms) {
            f32x4 s = zero4;
            const ushort_t* kr = &KsU[ms * 16 + l15][8 * lq];
            #pragma unroll
            for (int g = 0; g < 8; ++g)
                s = __builtin_amdgcn_mfma_f32_16x16x32_bf16(
                        qf[g], *(const bf16x8*)(kr + 32 * g), s, 0, 0, 0);
            sacc[ms] = s;
        }
        // scale + mask invalid m (C-layout: col = lane&15, row = 4*quad + reg)
        #pragma unroll
        for (int ms = 0; ms < 4; ++ms) {
            const bool inval = (m0 + ms * 16 + l15) >= MTOT;
            #pragma unroll
            for (int e = 0; e < 4; ++e)
                sacc[ms][e] = inval ? -1e30f : sacc[ms][e] * scale;
        }
        // online softmax: rows are wave-private; reduce across the 16-lane column group
        float mx[4];
        #pragma unroll
        for (int e = 0; e < 4; ++e) {
            float v = sacc[0][e];
            v = fmaxf(v, sacc[1][e]); v = fmaxf(v, sacc[2][e]); v = fmaxf(v, sacc[3][e]);
            mx[e] = v;
        }
        #pragma unroll
        for (int off = 1; off < 16; off <<= 1)
            #pragma unroll
            for (int e = 0; e < 4; ++e) mx[e] = fmaxf(mx[e], __shfl_xor(mx[e], off));

        float alpha[4], lsum[4];
        #pragma unroll
        for (int e = 0; e < 4; ++e) {
            float mn = fmaxf(m_st[e], mx[e]);
            alpha[e] = __expf(m_st[e] - mn);
            m_st[e] = mn;
            lsum[e] = 0.f;
        }
        #pragma unroll
        for (int ms = 0; ms < 4; ++ms)
            #pragma unroll
            for (int e = 0; e < 4; ++e) {
                float pj = __expf(sacc[ms][e] - m_st[e]);
                lsum[e] += pj;
                PsU[wave][4 * lq + e][ms * 16 + l15] = f2b(pj);
            }
        #pragma unroll
        for (int off = 1; off < 16; off <<= 1)
            #pragma unroll
            for (int e = 0; e < 4; ++e) lsum[e] += __shfl_xor(lsum[e], off);
        #pragma unroll
        for (int e = 0; e < 4; ++e) l_st[e] = l_st[e] * alpha[e] + lsum[e];

        // rescale O accumulators
        #pragma unroll
        for (int dt = 0; dt < 16; ++dt)
            #pragma unroll
            for (int e = 0; e < 4; ++e) oacc[dt][e] *= alpha[e];

        // ---- PV: A = P (16q x 64m) from per-wave LDS, B = Vs[d][m] (k = m contiguous) ----
        bf16x8 pf0 = *(const bf16x8*)&PsU[wave][l15][8 * lq];
        bf16x8 pf1 = *(const bf16x8*)&PsU[wave][l15][32 + 8 * lq];
        #pragma unroll
        for (int dt = 0; dt < 16; ++dt) {
            const ushort_t* vr = &VsU[dt * 16 + l15][8 * lq];
            oacc[dt] = __builtin_amdgcn_mfma_f32_16x16x32_bf16(
                           pf0, *(const bf16x8*)vr, oacc[dt], 0, 0, 0);
            oacc[dt] = __builtin_amdgcn_mfma_f32_16x16x32_bf16(
                           pf1, *(const bf16x8*)(vr + 32), oacc[dt], 0, 0, 0);
        }
    }

    // epilogue: O = oacc / l
    float linv[4];
    #pragma unroll
    for (int e = 0; e < 4; ++e) linv[e] = 1.f / l_st[e];
    ushort_t* ob = O + (size_t)(b * LSEQ) * HD + h * DH;
    #pragma unroll
    for (int e = 0; e < 4; ++e) {
        const int q = q0 + wave * 16 + 4 * lq + e;
        if (q < LSEQ) {
            #pragma unroll
            for (int dt = 0; dt < 16; ++dt)
                ob[(size_t)q * HD + dt * 16 + l15] = f2b(oacc[dt][e] * linv[e]);
        }
    }
}

// ---------------- residual + LayerNorm (no affine): Out = LN(X + R) ----------------
__global__ __launch_bounds__(256) void residual_ln(
    const float* __restrict__ X, const float* __restrict__ R, float* __restrict__ Out)
{
    const int row = blockIdx.x;
    const int t = threadIdx.x;
    const size_t base = (size_t)row * HID;
    float v = X[base + t] + R[base + t];
    float s = v, q = v * v;
    #pragma unroll
    for (int o = 32; o > 0; o >>= 1) {
        s += __shfl_xor(s, o, 64);
        q += __shfl_xor(q, o, 64);
    }
    __shared__ float ss[4], sq[4];
    const int wave = t >> 6, lane = t & 63;
    if (lane == 0) { ss[wave] = s; sq[wave] = q; }
    __syncthreads();
    s = ss[0] + ss[1] + ss[2] + ss[3];
    q = sq[0] + sq[1] + sq[2] + sq[3];
    float mean = s * (1.f / HID);
    float var  = q * (1.f / HID) - mean * mean;
    Out[base + t] = (v - mean) * rsqrtf(var + EPS);
}

// ---------------- launch ----------------
extern "C" void kernel_launch(void* const* d_in, const int* in_sizes, int n_in,
                              void* d_out, int out_size, void* d_ws, size_t ws_size,
                              hipStream_t stream) {
    const float* hidden = (const float*)d_in[1];
    const float* Wq = (const float*)d_in[2];  const float* bq = (const float*)d_in[3];
    const float* Wk = (const float*)d_in[4];  const float* bk = (const float*)d_in[5];
    const float* Wv = (const float*)d_in[6];  const float* bv = (const float*)d_in[7];
    const float* Wo = (const float*)d_in[8];  const float* bo = (const float*)d_in[9];
    const float* W1 = (const float*)d_in[10]; const float* b1 = (const float*)d_in[11];
    const float* W2 = (const float*)d_in[12]; const float* b2 = (const float*)d_in[13];
    float* out = (float*)d_out;

    constexpr size_t SZ_BF  = (size_t)MROWS * HD * 2;
    constexpr size_t SZ_F32 = (size_t)MROWS * HID * 4;
    constexpr size_t SZ_FFN = (size_t)MROWS * (4 * HID) * 4;
    char* ws = (char*)d_ws;
    size_t off = 0;
    __hip_bfloat16* kb = (__hip_bfloat16*)(ws + off); off += SZ_BF;
    __hip_bfloat16* vb = (__hip_bfloat16*)(ws + off); off += SZ_BF;
    __hip_bfloat16* qo = (__hip_bfloat16*)(ws + off); off += SZ_BF;
    float* attn1 = (float*)(ws + off); off += SZ_F32;
    float* attn2 = (float*)(ws + off); off += SZ_F32;
    float* proj  = (float*)(ws + off); off += SZ_F32;
    float* ffn   = (float*)(ws + off); off += SZ_FFN;
    if (ws_size < off) return;

    dim3 blk(256);
    const dim3 gProj(HD / 64, MROWS / 64);
    const dim3 gOut(HID / 64, MROWS / 64);
    const dim3 gF1(4 * HID / 64, MROWS / 64);
    const dim3 gA(4, BATCH * NH);   // 64-row q tiles x (b,h)

    // MHA1 (k/v shared with MHA2)
    gemm_bias<float, __hip_bfloat16, false><<<gProj, blk, 0, stream>>>(hidden, Wk, bk, kb, MROWS, HD, HID);
    gemm_bias<float, __hip_bfloat16, false><<<gProj, blk, 0, stream>>>(hidden, Wv, bv, vb, MROWS, HD, HID);
    gemm_bias<float, __hip_bfloat16, false><<<gProj, blk, 0, stream>>>(hidden, Wq, bq, qo, MROWS, HD, HID);
    attn_mfma<<<gA, blk, 0, stream>>>((const ushort_t*)qo, (const ushort_t*)kb,
                                      (const ushort_t*)vb, (ushort_t*)qo);
    gemm_bias<__hip_bfloat16, float, false><<<gOut, blk, 0, stream>>>(qo, Wo, bo, proj, MROWS, HID, HD);
    residual_ln<<<MROWS, blk, 0, stream>>>(proj, hidden, attn1);

    // MHA2 (q from attn1; k/v reused)
    gemm_bias<float, __hip_bfloat16, false><<<gProj, blk, 0, stream>>>(attn1, Wq, bq, qo, MROWS, HD, HID);
    attn_mfma<<<gA, blk, 0, stream>>>((const ushort_t*)qo, (const ushort_t*)kb,
                                      (const ushort_t*)vb, (ushort_t*)qo);
    gemm_bias<__hip_bfloat16, float, false><<<gOut, blk, 0, stream>>>(qo, Wo, bo, proj, MROWS, HID, HD);
    residual_ln<<<MROWS, blk, 0, stream>>>(proj, attn1, attn2);

    // FFN
    gemm_bias<float, float, true><<<gF1, blk, 0, stream>>>(attn2, W1, b1, ffn, MROWS, 4 * HID, HID);
    gemm_bias<float, float, false><<<gOut, blk, 0, stream>>>(ffn, W2, b2, proj, MROWS, HID, 4 * HID);
    residual_ln<<<MROWS, blk, 0, stream>>>(proj, attn2, out);
}